// Round 10
// baseline (5925.987 us; speedup 1.0000x reference)
//
#include <hip/hip_runtime.h>

// Problem constants (from reference)
#define EDIM 256
#define SLEN 64
#define TLEN 512
#define NT 512
#define NWAVES 8
#define BATCHES 128

// ---- wave/block reductions ----
__device__ __forceinline__ float wred_sum(float v) {
#pragma unroll
    for (int m = 32; m > 0; m >>= 1) v += __shfl_xor(v, m, 64);
    return v;
}
__device__ __forceinline__ float wred_max(float v) {
#pragma unroll
    for (int m = 32; m > 0; m >>= 1) v = fmaxf(v, __shfl_xor(v, m, 64));
    return v;
}
__device__ __forceinline__ float block_sum(float v, float* scr, int tid) {
    v = wred_sum(v);
    if ((tid & 63) == 0) scr[tid >> 6] = v;
    __syncthreads();
    if (tid == 0) {
        float s = scr[0];
#pragma unroll
        for (int i = 1; i < NWAVES; ++i) s += scr[i];
        scr[0] = s;
    }
    __syncthreads();
    float r = scr[0];
    __syncthreads();
    return r;
}
__device__ __forceinline__ float block_max(float v, float* scr, int tid) {
    v = wred_max(v);
    if ((tid & 63) == 0) scr[tid >> 6] = v;
    __syncthreads();
    if (tid == 0) {
        float s = scr[0];
#pragma unroll
        for (int i = 1; i < NWAVES; ++i) s = fmaxf(s, scr[i]);
        scr[0] = s;
    }
    __syncthreads();
    float r = scr[0];
    __syncthreads();
    return r;
}

// ---- pair sync primitives (device-scope, monotonic seq flags, fail-soft spin) ----
__device__ __forceinline__ void signal_flag(int* flag, int val) {
    __syncthreads();   // all data stores of this block issued (per-wave vmcnt drain at barrier)
    if (threadIdx.x == 0)
        __hip_atomic_store(flag, val, __ATOMIC_RELEASE, __HIP_MEMORY_SCOPE_AGENT);
}
__device__ __forceinline__ void wait_flag(int* flag, int val) {
    int spins = 0;
    while (__hip_atomic_load(flag, __ATOMIC_ACQUIRE, __HIP_MEMORY_SCOPE_AGENT) < val) {
        __builtin_amdgcn_s_sleep(2);
        if (++spins > 4000000) break;   // fail-soft: finite garbage instead of hang
    }
}

// ---- pre-pass: batched fp32 transpose  out[z][c][r] = in[z][r][c] ----
__global__ __launch_bounds__(256) void transpose_b_kernel(
    const float* __restrict__ in, float* __restrict__ out, int R, int C)
{
    __shared__ float tile[64][65];
    const float* inb = in + (size_t)blockIdx.z * R * C;
    float* outb = out + (size_t)blockIdx.z * R * C;
    const int r0 = blockIdx.y * 64;
    const int c0 = blockIdx.x * 64;
#pragma unroll
    for (int i = threadIdx.x; i < 64 * 64; i += 256) {
        int r = i >> 6, c = i & 63;
        tile[r][c] = inb[(size_t)(r0 + r) * C + (c0 + c)];
    }
    __syncthreads();
#pragma unroll
    for (int i = threadIdx.x; i < 64 * 64; i += 256) {
        int c = i >> 6, r = i & 63;
        outb[(size_t)(c0 + c) * R + (r0 + r)] = tile[r][c];
    }
}

__global__ __launch_bounds__(256) void zero_flags_kernel(int* __restrict__ flags) {
    flags[threadIdx.x] = 0;    // 256 flags
}

__global__ __launch_bounds__(NT) void gru_decoder_kernel(
    const float* __restrict__ signal,   // [B,T,E]
    const float* __restrict__ sigT,     // [B,E,T]
    const float* __restrict__ bases,    // [B,S,E]
    const int* __restrict__ mask,       // [B,T]
    const float* __restrict__ WwT,      // [E,E]
    const float* __restrict__ Wb,       // [E]
    const float* __restrict__ lng,      // [2E]
    const float* __restrict__ lnb,      // [2E]
    const float* __restrict__ wihT,     // [2E,3E]
    const float* __restrict__ bih,      // [3E]
    const float* __restrict__ whhT,     // [E,3E]
    const float* __restrict__ bhh,      // [3E]
    const float* __restrict__ hinit,    // [E]
    float* __restrict__ comm,           // [B,1024] exchange slots
    int* __restrict__ flags,            // [2,B] seq flags
    float* __restrict__ out)            // [B,S,E]
{
    const int bid   = blockIdx.x;
    const int batch = bid & (BATCHES - 1);
    const int side  = bid >> 7;              // partner = bid ^ 128 (same-XCD heuristic)
    const int tid   = threadIdx.x;

    __shared__ float h_s[EDIM];
    __shared__ float v_s[EDIM];
    __shared__ float vap[8 * EDIM];
    __shared__ float p_s[256];               // local (this side's 256 t)
    __shared__ float pbp[8 * 256];
    __shared__ float cxp[8 * EDIM];
    __shared__ float cxo[EDIM];              // own ctx partial
    __shared__ float inp_s[2 * EDIM];
    __shared__ float inpn_s[2 * EDIM];
    __shared__ float gxp[4 * 384];
    __shared__ float ghp[4 * 384];
    __shared__ float scr[NWAVES];

    const float* sigb  = signal + (size_t)batch * TLEN * EDIM;
    const float* sigTb = sigT + (size_t)batch * EDIM * TLEN;
    const int*   maskb = mask + (size_t)batch * TLEN + side * 256;

    float* commB = comm + (size_t)batch * 1024;
    float* ctx_own = commB + side * 256;
    float* ctx_par = commB + (1 - side) * 256;
    float* ms_own  = commB + 512 + side * 2;
    float* ms_par  = commB + 512 + (1 - side) * 2;
    float* h_own   = commB + 640 + side * 128;
    float* h_par   = commB + 640 + (1 - side) * 128;
    int* flag_own  = flags + side * BATCHES + batch;
    int* flag_par  = flags + (1 - side) * BATCHES + batch;

    if (tid < EDIM) h_s[tid] = hinit[tid];
    __syncthreads();

    for (int s = 0; s < SLEN; ++s) {
        // ---- Phase A (redundant both sides): v = Ww@h + Wb; 8-way k-split, 4 rows/thread
        {
            const int q  = tid >> 6;
            const int r4 = (tid & 63) * 4;
            const float* base = WwT + (size_t)(q * 32) * EDIM + r4;
            const float* xk = &h_s[q * 32];
            float a0 = 0.f, a1 = 0.f, a2 = 0.f, a3 = 0.f;
#pragma unroll 8
            for (int k = 0; k < 32; ++k) {
                float4 w4 = *reinterpret_cast<const float4*>(base + (size_t)k * EDIM);
                float x = xk[k];
                a0 += w4.x * x; a1 += w4.y * x; a2 += w4.z * x; a3 += w4.w * x;
            }
            vap[q * EDIM + r4 + 0] = a0;
            vap[q * EDIM + r4 + 1] = a1;
            vap[q * EDIM + r4 + 2] = a2;
            vap[q * EDIM + r4 + 3] = a3;
        }
        __syncthreads();
        if (tid < EDIM) {
            float v = Wb[tid];
#pragma unroll
            for (int q = 0; q < 8; ++q) v += vap[q * EDIM + tid];
            v_s[tid] = v;
        }
        __syncthreads();

        // ---- Phase B (own t-half, 256 t): 64 t4-slots x 8 k-splits (32 k each)
        {
            const int q  = tid >> 6;
            const int t4 = (tid & 63) * 4;
            const float* base = sigTb + (size_t)(q * 32) * TLEN + side * 256 + t4;
            const float* vk = &v_s[q * 32];
            float a0 = 0.f, a1 = 0.f, a2 = 0.f, a3 = 0.f;
#pragma unroll 8
            for (int k = 0; k < 32; ++k) {
                float4 w4 = *reinterpret_cast<const float4*>(base + (size_t)k * TLEN);
                float x = vk[k];
                a0 += w4.x * x; a1 += w4.y * x; a2 += w4.z * x; a3 += w4.w * x;
            }
            pbp[q * 256 + t4 + 0] = a0;
            pbp[q * 256 + t4 + 1] = a1;
            pbp[q * 256 + t4 + 2] = a2;
            pbp[q * 256 + t4 + 3] = a3;
        }
        __syncthreads();

        // ---- local softmax stats over this half (flash-combine later) ----
        float e0 = -1e30f;
        if (tid < 256) {
            float e = 0.f;
#pragma unroll
            for (int q = 0; q < 8; ++q) e += pbp[q * 256 + tid];
            e0 = maskb[tid] ? -1e30f : e;
        }
        float Ml = block_max(e0, scr, tid);
        float ex = (tid < 256) ? __expf(e0 - Ml) : 0.f;
        if (tid < 256) p_s[tid] = ex;
        float Sl = block_sum(ex, scr, tid);     // internal barrier publishes p_s

        // ---- Phase C (own t-half): ctx partial; 64 e4-slots x 8 t-splits (32 t each)
        {
            const int q  = tid >> 6;
            const int e4 = (tid & 63) * 4;
            const float* base = sigb + (size_t)(side * 256 + q * 32) * EDIM + e4;
            const float* pk = &p_s[q * 32];
            float a0 = 0.f, a1 = 0.f, a2 = 0.f, a3 = 0.f;
#pragma unroll 8
            for (int t = 0; t < 32; ++t) {
                float4 w4 = *reinterpret_cast<const float4*>(base + (size_t)t * EDIM);
                float p = pk[t];
                a0 += w4.x * p; a1 += w4.y * p; a2 += w4.z * p; a3 += w4.w * p;
            }
            cxp[q * EDIM + e4 + 0] = a0;
            cxp[q * EDIM + e4 + 1] = a1;
            cxp[q * EDIM + e4 + 2] = a2;
            cxp[q * EDIM + e4 + 3] = a3;
        }
        __syncthreads();
        if (tid < EDIM) {
            float c = 0.f;
#pragma unroll
            for (int q = 0; q < 8; ++q) c += cxp[q * EDIM + tid];
            cxo[tid] = c;
            ctx_own[tid] = c;
        }
        if (tid == 0) { ms_own[0] = Ml; ms_own[1] = Sl; }

        // ---- SYNC1: exchange ctx partial + (M,S) ----
        signal_flag(flag_own, 2 * s + 1);
        wait_flag(flag_par, 2 * s + 1);

        // ---- combine (both sides, exact softmax algebra) + bases -> inp ----
        {
            float Mp = ms_par[0], Sp = ms_par[1];
            float Mf = fmaxf(Ml, Mp);
            float al = __expf(Ml - Mf), ap = __expf(Mp - Mf);
            float inv = 1.0f / (Sl * al + Sp * ap);
            if (tid < 256) {
                inp_s[tid] = bases[((size_t)batch * SLEN + s) * EDIM + tid];
            } else {
                int e = tid - 256;
                inp_s[EDIM + e] = (cxo[e] * al + ctx_par[e] * ap) * inv;
            }
        }
        __syncthreads();

        // ---- LayerNorm over 2E=512 ----
        float val = inp_s[tid];
        float mu  = block_sum(val, scr, tid) * (1.0f / (2 * EDIM));
        float dv  = val - mu;
        float var = block_sum(dv * dv, scr, tid) * (1.0f / (2 * EDIM));
        float rs  = rsqrtf(var + 1e-5f);
        inpn_s[tid] = dv * rs * lng[tid] + lnb[tid];
        __syncthreads();

        // ---- Phase D (own j-half): gx rows {j, 256+j, 512+j} and gh rows, j in side half.
        //      gx: 96 float4-slots x 4 k-quarters (128 k)  = 384 workers
        //      gh: 96 float4-slots x 4 k-quarters (64 k)   = 384 workers
        //      round 0: w=tid (gx:0..383, gh:384..511->g 0..127); round 1: tid<256 -> g 128..383
#pragma unroll
        for (int rd = 0; rd < 2; ++rd) {
            int w = rd * NT + tid;
            if (w < 384) {                       // gx worker
                int q = w / 96, sl = w - q * 96;
                int band = sl >> 5;
                int m4 = band * 256 + (sl & 31) * 4 + side * 128;
                const float* base = wihT + (size_t)(q * 128) * 768 + m4;
                const float* xk = &inpn_s[q * 128];
                float a0 = 0.f, a1 = 0.f, a2 = 0.f, a3 = 0.f;
#pragma unroll 8
                for (int k = 0; k < 128; ++k) {
                    float4 w4 = *reinterpret_cast<const float4*>(base + (size_t)k * 768);
                    float x = xk[k];
                    a0 += w4.x * x; a1 += w4.y * x; a2 += w4.z * x; a3 += w4.w * x;
                }
                int l = band * 128 + (sl & 31) * 4;
                gxp[q * 384 + l + 0] = a0;
                gxp[q * 384 + l + 1] = a1;
                gxp[q * 384 + l + 2] = a2;
                gxp[q * 384 + l + 3] = a3;
            } else if (w < 768) {                // gh worker
                int g = w - 384;
                int q = g / 96, sl = g - q * 96;
                int band = sl >> 5;
                int m4 = band * 256 + (sl & 31) * 4 + side * 128;
                const float* base = whhT + (size_t)(q * 64) * 768 + m4;
                const float* xk = &h_s[q * 64];
                float a0 = 0.f, a1 = 0.f, a2 = 0.f, a3 = 0.f;
#pragma unroll 8
                for (int k = 0; k < 64; ++k) {
                    float4 w4 = *reinterpret_cast<const float4*>(base + (size_t)k * 768);
                    float x = xk[k];
                    a0 += w4.x * x; a1 += w4.y * x; a2 += w4.z * x; a3 += w4.w * x;
                }
                int l = band * 128 + (sl & 31) * 4;
                ghp[q * 384 + l + 0] = a0;
                ghp[q * 384 + l + 1] = a1;
                ghp[q * 384 + l + 2] = a2;
                ghp[q * 384 + l + 3] = a3;
            }
        }
        __syncthreads();

        // ---- Phase E (own j-half): gates, h update, out; torch gate order r,z,n ----
        if (tid < 128) {
            int j = tid, jg = side * 128 + j;
            float xr = bih[jg], xz = bih[EDIM + jg], xn = bih[2 * EDIM + jg];
            float hr = bhh[jg], hz = bhh[EDIM + jg], hn_ = bhh[2 * EDIM + jg];
#pragma unroll
            for (int q = 0; q < 4; ++q) {
                xr  += gxp[q * 384 + j];
                xz  += gxp[q * 384 + 128 + j];
                xn  += gxp[q * 384 + 256 + j];
                hr  += ghp[q * 384 + j];
                hz  += ghp[q * 384 + 128 + j];
                hn_ += ghp[q * 384 + 256 + j];
            }
            float r = 1.0f / (1.0f + __expf(-(xr + hr)));
            float z = 1.0f / (1.0f + __expf(-(xz + hz)));
            float n = tanhf(xn + r * hn_);
            float hnew = (1.0f - z) * n + z * h_s[jg];
            h_s[jg] = hnew;
            out[((size_t)batch * SLEN + s) * EDIM + jg] = hnew;
            h_own[j] = hnew;
        }

        // ---- SYNC2: exchange h halves ----
        signal_flag(flag_own, 2 * s + 2);
        wait_flag(flag_par, 2 * s + 2);
        if (tid < 128) h_s[(1 - side) * 128 + tid] = h_par[tid];
        __syncthreads();
    }
}

extern "C" void kernel_launch(void* const* d_in, const int* in_sizes, int n_in,
                              void* d_out, int out_size, void* d_ws, size_t ws_size,
                              hipStream_t stream) {
    const float* signal = (const float*)d_in[0];
    const float* bases  = (const float*)d_in[1];
    const int*   mask   = (const int*)d_in[2];
    const float* Ww     = (const float*)d_in[3];
    const float* Wb     = (const float*)d_in[4];
    const float* lng    = (const float*)d_in[5];
    const float* lnb    = (const float*)d_in[6];
    const float* wih    = (const float*)d_in[7];
    const float* bih    = (const float*)d_in[8];
    const float* whh    = (const float*)d_in[9];
    const float* bhh    = (const float*)d_in[10];
    const float* hinit  = (const float*)d_in[11];
    float*       out    = (float*)d_out;

    const int B = in_sizes[0] / (TLEN * EDIM);   // 128

    // ws layout (fp32): sigT[B,E,T] | WwT | wihT | whhT | comm[B,1024] | flags[256]
    float* sigT  = (float*)d_ws;
    float* WwT   = sigT + (size_t)B * EDIM * TLEN;
    float* wihT  = WwT + EDIM * EDIM;
    float* whhT  = wihT + (2 * EDIM) * (3 * EDIM);
    float* comm  = whhT + EDIM * (3 * EDIM);
    int*   flags = (int*)(comm + (size_t)B * 1024);

    transpose_b_kernel<<<dim3(EDIM / 64, TLEN / 64, B), 256, 0, stream>>>(signal, sigT, TLEN, EDIM);
    transpose_b_kernel<<<dim3(EDIM / 64, EDIM / 64, 1), 256, 0, stream>>>(Ww, WwT, EDIM, EDIM);
    transpose_b_kernel<<<dim3(2 * EDIM / 64, 3 * EDIM / 64, 1), 256, 0, stream>>>(wih, wihT, 3 * EDIM, 2 * EDIM);
    transpose_b_kernel<<<dim3(EDIM / 64, 3 * EDIM / 64, 1), 256, 0, stream>>>(whh, whhT, 3 * EDIM, EDIM);
    zero_flags_kernel<<<1, 256, 0, stream>>>(flags);

    gru_decoder_kernel<<<dim3(2 * B), dim3(NT), 0, stream>>>(
        signal, sigT, bases, mask, WwT, Wb, lng, lnb, wihT, bih, whhT, bhh, hinit,
        comm, flags, out);
}

// Round 11
// 3814.449 us; speedup vs baseline: 1.5536x; 1.5536x over previous
//
#include <hip/hip_runtime.h>

// Problem constants (from reference)
#define EDIM 256
#define SLEN 64
#define TLEN 512
#define NT 512
#define NWAVES 8
#define TILE_T 64
#define NTILES (TLEN / TILE_T)

// ---- wave/block reductions ----
__device__ __forceinline__ float wred_sum(float v) {
#pragma unroll
    for (int m = 32; m > 0; m >>= 1) v += __shfl_xor(v, m, 64);
    return v;
}
__device__ __forceinline__ float wred_max(float v) {
#pragma unroll
    for (int m = 32; m > 0; m >>= 1) v = fmaxf(v, __shfl_xor(v, m, 64));
    return v;
}
__device__ __forceinline__ float block_sum(float v, float* scr, int tid) {
    v = wred_sum(v);
    if ((tid & 63) == 0) scr[tid >> 6] = v;
    __syncthreads();
    if (tid == 0) {
        float s = scr[0];
#pragma unroll
        for (int i = 1; i < NWAVES; ++i) s += scr[i];
        scr[0] = s;
    }
    __syncthreads();
    float r = scr[0];
    __syncthreads();
    return r;
}

// ---- pre-pass: fp32 transpose out[c][r] = in[r][c] ----
__global__ __launch_bounds__(256) void transpose_b_kernel(
    const float* __restrict__ in, float* __restrict__ out, int R, int C)
{
    __shared__ float tile[64][65];
    const int r0 = blockIdx.y * 64;
    const int c0 = blockIdx.x * 64;
#pragma unroll
    for (int i = threadIdx.x; i < 64 * 64; i += 256) {
        int r = i >> 6, c = i & 63;
        tile[r][c] = in[(size_t)(r0 + r) * C + (c0 + c)];
    }
    __syncthreads();
#pragma unroll
    for (int i = threadIdx.x; i < 64 * 64; i += 256) {
        int c = i >> 6, r = i & 63;
        out[(size_t)(c0 + c) * R + (r0 + r)] = tile[r][c];
    }
}

__global__ __launch_bounds__(NT) void gru_decoder_kernel(
    const float* __restrict__ signal,   // [B,T,E] fp32 (single layout, streamed once/step)
    const float* __restrict__ bases,    // [B,S,E]
    const int* __restrict__ mask,       // [B,T] int32 (nonzero = masked)
    const float* __restrict__ WwT,      // [E,E]   WwT[k][j] = Ww[j][k]
    const float* __restrict__ Wb,       // [E]
    const float* __restrict__ lng,      // [2E]
    const float* __restrict__ lnb,      // [2E]
    const float* __restrict__ wihT,     // [2E,3E]
    const float* __restrict__ bih,      // [3E]
    const float* __restrict__ whhT,     // [E,3E]
    const float* __restrict__ bhh,      // [3E]
    const float* __restrict__ hinit,    // [E]
    float* __restrict__ out)            // [B,S,E]
{
    const int b    = blockIdx.x;
    const int tid  = threadIdx.x;
    const int lane = tid & 63;
    const int wave = tid >> 6;

    __shared__ float tile[TILE_T * EDIM];   // 64 KB signal tile
    __shared__ float h_s[EDIM];
    __shared__ float v_s[EDIM];
    __shared__ float vap[8 * EDIM];
    __shared__ float e_s[TILE_T];
    __shared__ float p_t[TILE_T];
    __shared__ float msum[2];               // {M_new, sum_p} broadcast
    __shared__ float cxp[2 * EDIM];
    __shared__ float inp_s[2 * EDIM];
    __shared__ float inpn_s[2 * EDIM];
    __shared__ float gxp[4 * 768];
    __shared__ float ghp[4 * 768];
    __shared__ float scr[NWAVES];

    const float* sigb  = signal + (size_t)b * TLEN * EDIM;
    const int*   maskb = mask + (size_t)b * TLEN;

    if (tid < EDIM) h_s[tid] = hinit[tid];
    __syncthreads();

    for (int s = 0; s < SLEN; ++s) {
        // ---- Phase A: v = Ww @ h + Wb (8-way k-split, 4 rows/thread, float4) ----
        {
            const int q  = wave;                 // 0..7
            const int r4 = lane * 4;             // 0..252
            const float* base = WwT + (size_t)(q * 32) * EDIM + r4;
            const float* xk = &h_s[q * 32];
            float a0 = 0.f, a1 = 0.f, a2 = 0.f, a3 = 0.f;
#pragma unroll 8
            for (int k = 0; k < 32; ++k) {
                float4 w4 = *reinterpret_cast<const float4*>(base + (size_t)k * EDIM);
                float x = xk[k];
                a0 += w4.x * x; a1 += w4.y * x; a2 += w4.z * x; a3 += w4.w * x;
            }
            vap[q * EDIM + r4 + 0] = a0;
            vap[q * EDIM + r4 + 1] = a1;
            vap[q * EDIM + r4 + 2] = a2;
            vap[q * EDIM + r4 + 3] = a3;
        }
        if (tid < EDIM) inp_s[tid] = bases[((size_t)b * SLEN + s) * EDIM + tid];
        __syncthreads();
        if (tid < EDIM) {
            float v = Wb[tid];
#pragma unroll
            for (int q = 0; q < 8; ++q) v += vap[q * EDIM + tid];
            v_s[tid] = v;
        }
        __syncthreads();

        // ---- Fused B+C: single pass over signal, online softmax (exact) ----
        float4 vfrag = *reinterpret_cast<const float4*>(&v_s[lane * 4]);
        const int e_own  = tid & 255;
        const int t_half = tid >> 8;            // 0/1 -> 32-t half of each tile
        float ctx_acc = 0.f;
        float M_run = -1e30f, S_run = 0.f;

#pragma unroll 1
        for (int tt = 0; tt < NTILES; ++tt) {
            const int t0 = tt * TILE_T;
            // stage tile (coalesced float4; 8 per thread)
            {
                const float4* src = reinterpret_cast<const float4*>(sigb + (size_t)t0 * EDIM);
                float4* dst = reinterpret_cast<float4*>(tile);
#pragma unroll
                for (int j = 0; j < (TILE_T * EDIM / 4) / NT; ++j)
                    dst[tid + j * NT] = src[tid + j * NT];
            }
            __syncthreads();
            // scores: 8 t per wave, dot from LDS + wred_sum
#pragma unroll
            for (int i = 0; i < TILE_T / NWAVES; ++i) {
                int t = wave * (TILE_T / NWAVES) + i;
                float4 s4 = reinterpret_cast<const float4*>(tile + t * EDIM)[lane];
                float d = s4.x * vfrag.x + s4.y * vfrag.y + s4.z * vfrag.z + s4.w * vfrag.w;
                d = wred_sum(d);
                if (lane == 0) e_s[t] = d;
            }
            __syncthreads();
            // wave 0: tile max, p_t, sum_p (masked -> p=0 explicitly; no inf path)
            if (wave == 0) {
                bool msk = maskb[t0 + lane] != 0;
                float e  = msk ? -1e30f : e_s[lane];
                float mt = wred_max(e);
                float Mn = fmaxf(M_run, mt);
                float p  = msk ? 0.f : __expf(e - Mn);
                p_t[lane] = p;
                float sp = wred_sum(p);
                if (lane == 0) { msum[0] = Mn; msum[1] = sp; }
            }
            __syncthreads();
            // all threads: uniform online update + ctx accumulate (2 threads/e)
            {
                float Mn = msum[0], sp = msum[1];
                float alpha = __expf(M_run - Mn);
                M_run = Mn;
                S_run = S_run * alpha + sp;
                ctx_acc *= alpha;
                const float* tcol = tile + (t_half * 32) * EDIM + e_own;
                const float* pk = &p_t[t_half * 32];
#pragma unroll 8
                for (int t = 0; t < 32; ++t)
                    ctx_acc += pk[t] * tcol[t * EDIM];   // 2-way bank alias: free
            }
            __syncthreads();   // tile/p_t consumed; safe to overwrite next iter
        }
        cxp[tid] = ctx_acc;
        __syncthreads();
        if (tid >= EDIM) {
            int e = tid - EDIM;
            inp_s[EDIM + e] = (cxp[e] + cxp[EDIM + e]) / S_run;
        }
        __syncthreads();

        // ---- LayerNorm over 2E=512 ----
        float val = inp_s[tid];
        float mu  = block_sum(val, scr, tid) * (1.0f / (2 * EDIM));
        float dv  = val - mu;
        float var = block_sum(dv * dv, scr, tid) * (1.0f / (2 * EDIM));
        float rs  = rsqrtf(var + 1e-5f);
        inpn_s[tid] = dv * rs * lng[tid] + lnb[tid];
        __syncthreads();

        // ---- Phase D: gx = wih@inpn (768x512), gh = whh@h (768x256); as R9 ----
#pragma unroll
        for (int rd = 0; rd < 3; ++rd) {
            int w = rd * NT + tid;              // 0..1535
            if (w < 768) {                      // gx worker
                int q  = w / 192;               // k in [q*128, q*128+128)
                int r4 = (w - q * 192) * 4;
                const float* base = wihT + (size_t)(q * 128) * 768 + r4;
                const float* xk = &inpn_s[q * 128];
                float a0 = 0.f, a1 = 0.f, a2 = 0.f, a3 = 0.f;
#pragma unroll 8
                for (int k = 0; k < 128; ++k) {
                    float4 w4 = *reinterpret_cast<const float4*>(base + (size_t)k * 768);
                    float x = xk[k];
                    a0 += w4.x * x; a1 += w4.y * x; a2 += w4.z * x; a3 += w4.w * x;
                }
                gxp[q * 768 + r4 + 0] = a0;
                gxp[q * 768 + r4 + 1] = a1;
                gxp[q * 768 + r4 + 2] = a2;
                gxp[q * 768 + r4 + 3] = a3;
            } else {                            // gh worker
                int w2 = w - 768;
                int q  = w2 / 192;              // k in [q*64, q*64+64)
                int r4 = (w2 - q * 192) * 4;
                const float* base = whhT + (size_t)(q * 64) * 768 + r4;
                const float* xk = &h_s[q * 64];
                float a0 = 0.f, a1 = 0.f, a2 = 0.f, a3 = 0.f;
#pragma unroll 8
                for (int k = 0; k < 64; ++k) {
                    float4 w4 = *reinterpret_cast<const float4*>(base + (size_t)k * 768);
                    float x = xk[k];
                    a0 += w4.x * x; a1 += w4.y * x; a2 += w4.z * x; a3 += w4.w * x;
                }
                ghp[q * 768 + r4 + 0] = a0;
                ghp[q * 768 + r4 + 1] = a1;
                ghp[q * 768 + r4 + 2] = a2;
                ghp[q * 768 + r4 + 3] = a3;
            }
        }
        __syncthreads();

        // ---- Phase E: gates, h update, output (torch gate order r,z,n) ----
        if (tid < EDIM) {
            int j = tid;
            float xr = bih[j], xz = bih[EDIM + j], xn = bih[2 * EDIM + j];
            float hr = bhh[j], hz = bhh[EDIM + j], hn_ = bhh[2 * EDIM + j];
#pragma unroll
            for (int q = 0; q < 4; ++q) {
                xr  += gxp[q * 768 + j];
                xz  += gxp[q * 768 + EDIM + j];
                xn  += gxp[q * 768 + 2 * EDIM + j];
                hr  += ghp[q * 768 + j];
                hz  += ghp[q * 768 + EDIM + j];
                hn_ += ghp[q * 768 + 2 * EDIM + j];
            }
            float r = 1.0f / (1.0f + __expf(-(xr + hr)));
            float z = 1.0f / (1.0f + __expf(-(xz + hz)));
            float n = tanhf(xn + r * hn_);
            float hnew = (1.0f - z) * n + z * h_s[j];
            h_s[j] = hnew;
            out[((size_t)b * SLEN + s) * EDIM + j] = hnew;
        }
        __syncthreads();
    }
}

extern "C" void kernel_launch(void* const* d_in, const int* in_sizes, int n_in,
                              void* d_out, int out_size, void* d_ws, size_t ws_size,
                              hipStream_t stream) {
    const float* signal = (const float*)d_in[0];
    const float* bases  = (const float*)d_in[1];
    const int*   mask   = (const int*)d_in[2];
    const float* Ww     = (const float*)d_in[3];
    const float* Wb     = (const float*)d_in[4];
    const float* lng    = (const float*)d_in[5];
    const float* lnb    = (const float*)d_in[6];
    const float* wih    = (const float*)d_in[7];
    const float* bih    = (const float*)d_in[8];
    const float* whh    = (const float*)d_in[9];
    const float* bhh    = (const float*)d_in[10];
    const float* hinit  = (const float*)d_in[11];
    float*       out    = (float*)d_out;

    const int B = in_sizes[0] / (TLEN * EDIM);   // 128

    // workspace (fp32): WwT[E,E] | wihT[2E,3E] | whhT[E,3E]  (no signal copies)
    float* WwT  = (float*)d_ws;
    float* wihT = WwT + EDIM * EDIM;
    float* whhT = wihT + (2 * EDIM) * (3 * EDIM);

    transpose_b_kernel<<<dim3(EDIM / 64, EDIM / 64), 256, 0, stream>>>(Ww, WwT, EDIM, EDIM);
    transpose_b_kernel<<<dim3(2 * EDIM / 64, 3 * EDIM / 64), 256, 0, stream>>>(wih, wihT, 3 * EDIM, 2 * EDIM);
    transpose_b_kernel<<<dim3(EDIM / 64, 3 * EDIM / 64), 256, 0, stream>>>(whh, whhT, 3 * EDIM, EDIM);

    gru_decoder_kernel<<<dim3(B), dim3(NT), 0, stream>>>(
        signal, bases, mask, WwT, Wb, lng, lnb, wihT, bih, whhT, bhh, hinit, out);
}